// Round 1
// baseline (904.373 us; speedup 1.0000x reference)
//
#include <hip/hip_runtime.h>

typedef _Float16 f16;
typedef _Float16 f16x4 __attribute__((ext_vector_type(4)));
typedef _Float16 f16x8 __attribute__((ext_vector_type(8)));
typedef float f32x4 __attribute__((ext_vector_type(4)));

#define S_LEN 2048
#define DKH 64
#define NH 16
#define DMODEL 1024
#define LDSA 40   // f16 elems per LDS row: 32 data + 4 pad (80 B, mult of 16)
#define KLDS 72   // f16 elems per LDS row: 64 data + 8 pad (144 B, mult of 16)

static __device__ __forceinline__ f32x4 mfma16(f16x8 a, f16x8 b, f32x4 c) {
    return __builtin_amdgcn_mfma_f32_16x16x32_f16(a, b, c, 0, 0, 0);
}

// ---------------- Projection GEMM: C = X @ W^T + b, scattered to head layouts (f16)
// z=0: Q -> [bh][s][dk]; z=1: K -> [bh][s][dk]; z=2: V -> [bh][dk][s] (transposed)
__global__ __launch_bounds__(256)
void proj_gemm(const float* __restrict__ xq, const float* __restrict__ xk, const float* __restrict__ xv,
               const float* __restrict__ wq, const float* __restrict__ wk, const float* __restrict__ wv,
               const float* __restrict__ bq, const float* __restrict__ bk, const float* __restrict__ bv,
               f16* __restrict__ oq, f16* __restrict__ ok, f16* __restrict__ ov)
{
    const int z = blockIdx.z;
    const float* X  = (z == 0) ? xq : (z == 1) ? xk : xv;
    const float* W  = (z == 0) ? wq : (z == 1) ? wk : wv;
    const float* Bb = (z == 0) ? bq : (z == 1) ? bk : bv;
    f16* O          = (z == 0) ? oq : (z == 1) ? ok : ov;

    __shared__ f16 As[128 * LDSA];
    __shared__ f16 Bs[128 * LDSA];

    const int t = threadIdx.x;
    const int lane = t & 63;
    const int w = t >> 6;
    const int wr = w >> 1, wc = w & 1;
    const int g = lane >> 4;
    const int l16 = lane & 15;

    const int m0 = blockIdx.y * 128;
    const int n0 = blockIdx.x * 128;

    f32x4 acc[4][4] = {};

    const int srow = t >> 3;   // 0..31
    const int skq  = t & 7;    // float4 quarter within 32-wide k

    for (int k0 = 0; k0 < DMODEL; k0 += 32) {
#pragma unroll
        for (int it = 0; it < 4; ++it) {
            int r = srow + it * 32;
            float4 va = *(const float4*)(X + (size_t)(m0 + r) * DMODEL + k0 + skq * 4);
            f16x4 ha = { (f16)va.x, (f16)va.y, (f16)va.z, (f16)va.w };
            *(f16x4*)(As + r * LDSA + skq * 4) = ha;
            float4 vb = *(const float4*)(W + (size_t)(n0 + r) * DMODEL + k0 + skq * 4);
            f16x4 hb = { (f16)vb.x, (f16)vb.y, (f16)vb.z, (f16)vb.w };
            *(f16x4*)(Bs + r * LDSA + skq * 4) = hb;
        }
        __syncthreads();
        f16x8 af[4], bf[4];
#pragma unroll
        for (int i = 0; i < 4; ++i) {
            af[i] = *(const f16x8*)(As + (wr * 64 + i * 16 + l16) * LDSA + g * 8);
            bf[i] = *(const f16x8*)(Bs + (wc * 64 + i * 16 + l16) * LDSA + g * 8);
        }
#pragma unroll
        for (int i = 0; i < 4; ++i)
#pragma unroll
            for (int j = 0; j < 4; ++j)
                acc[i][j] = mfma16(af[i], bf[j], acc[i][j]);
        __syncthreads();
    }

#pragma unroll
    for (int j = 0; j < 4; ++j) {
        int n = n0 + wc * 64 + j * 16 + l16;
        float bias = Bb[n];
        int h = n >> 6, dk = n & 63;
#pragma unroll
        for (int i = 0; i < 4; ++i) {
#pragma unroll
            for (int r = 0; r < 4; ++r) {
                int m = m0 + wr * 64 + i * 16 + g * 4 + r;
                float val = acc[i][j][r] + bias;
                int bb = m >> 11, s = m & 2047;
                size_t headbase = (size_t)(bb * NH + h) * (S_LEN * DKH);
                if (z < 2) O[headbase + (size_t)s * DKH + dk] = (f16)val;
                else       O[headbase + (size_t)dk * S_LEN + s] = (f16)val;
            }
        }
    }
}

// ---------------- Fused attention: per (bh, 128-q-tile). Two-pass softmax.
// Writes normalized attn (fp32) to global and O = P@V (f16) to OH workspace.
__global__ __launch_bounds__(256)
void attn_kernel(const f16* __restrict__ Q, const f16* __restrict__ K, const f16* __restrict__ Vt,
                 float* __restrict__ attn, f16* __restrict__ OH)
{
    __shared__ f16 Ks[64 * KLDS];
    __shared__ f16 Vs[64 * KLDS];
    __shared__ f16 Ps[128 * KLDS];

    const int t = threadIdx.x;
    const int lane = t & 63;
    const int w = t >> 6;           // wave 0..3 -> q rows w*32..w*32+31
    const int g = lane >> 4;
    const int l16 = lane & 15;

    const int bh = blockIdx.y;
    const int q0 = blockIdx.x * 128;

    const f16* Qh = Q  + (size_t)bh * (S_LEN * DKH);
    const f16* Kh = K  + (size_t)bh * (S_LEN * DKH);
    const f16* Vh = Vt + (size_t)bh * (S_LEN * DKH);
    float* attn_h = attn + (size_t)bh * S_LEN * S_LEN;

    const float sc = 0.125f * 1.44269504088896341f;  // 1/sqrt(dk) * log2(e)

    // Q fragments held in registers for the whole kernel
    f16x8 qf_[2][2];
#pragma unroll
    for (int qf = 0; qf < 2; ++qf)
#pragma unroll
        for (int ks = 0; ks < 2; ++ks)
            qf_[qf][ks] = *(const f16x8*)(Qh + (size_t)(q0 + w * 32 + qf * 16 + l16) * DKH + ks * 32 + g * 8);

    float m_[2][4], l_[2][4];
#pragma unroll
    for (int qf = 0; qf < 2; ++qf)
#pragma unroll
        for (int r = 0; r < 4; ++r) { m_[qf][r] = -1.0e30f; l_[qf][r] = 0.0f; }

    // ---- Pass A: per-lane online max/sum over all keys
    for (int kt = 0; kt < S_LEN / 64; ++kt) {
        const int key0 = kt * 64;
        __syncthreads();
#pragma unroll
        for (int it = 0; it < 2; ++it) {
            int r = (t >> 3) + it * 32;
            f16x8 v = *(const f16x8*)(Kh + (size_t)(key0 + r) * DKH + (t & 7) * 8);
            *(f16x8*)(Ks + r * KLDS + (t & 7) * 8) = v;
        }
        __syncthreads();

        f32x4 sacc[2][4] = {};
#pragma unroll
        for (int ks = 0; ks < 2; ++ks) {
            f16x8 bk[4];
#pragma unroll
            for (int kf = 0; kf < 4; ++kf)
                bk[kf] = *(const f16x8*)(Ks + (kf * 16 + l16) * KLDS + ks * 32 + g * 8);
#pragma unroll
            for (int qfi = 0; qfi < 2; ++qfi)
#pragma unroll
                for (int kf = 0; kf < 4; ++kf)
                    sacc[qfi][kf] = mfma16(qf_[qfi][ks], bk[kf], sacc[qfi][kf]);
        }
#pragma unroll
        for (int qfi = 0; qfi < 2; ++qfi)
#pragma unroll
            for (int r = 0; r < 4; ++r) {
                float s0 = sacc[qfi][0][r] * sc;
                float s1 = sacc[qfi][1][r] * sc;
                float s2 = sacc[qfi][2][r] * sc;
                float s3 = sacc[qfi][3][r] * sc;
                float mx = fmaxf(fmaxf(s0, s1), fmaxf(s2, s3));
                float mo = m_[qfi][r];
                float mn = fmaxf(mo, mx);
                float corr = exp2f(mo - mn);
                l_[qfi][r] = l_[qfi][r] * corr +
                             exp2f(s0 - mn) + exp2f(s1 - mn) + exp2f(s2 - mn) + exp2f(s3 - mn);
                m_[qfi][r] = mn;
            }
    }

    // cross-lane merge within each 16-lane group (all hold same rows)
#pragma unroll
    for (int qfi = 0; qfi < 2; ++qfi)
#pragma unroll
        for (int r = 0; r < 4; ++r) {
            float m = m_[qfi][r], l = l_[qfi][r];
#pragma unroll
            for (int off = 1; off < 16; off <<= 1) {
                float mo = __shfl_xor(m, off);
                float lo = __shfl_xor(l, off);
                float mn = fmaxf(m, mo);
                l = l * exp2f(m - mn) + lo * exp2f(mo - mn);
                m = mn;
            }
            m_[qfi][r] = m;
            l_[qfi][r] = 1.0f / l;   // store reciprocal of denom
        }

    // ---- Pass B: recompute scores, write attn, accumulate O = P @ V
    f32x4 oacc[2][4] = {};
    for (int kt = 0; kt < S_LEN / 64; ++kt) {
        const int key0 = kt * 64;
        __syncthreads();
#pragma unroll
        for (int it = 0; it < 2; ++it) {
            int r = (t >> 3) + it * 32;
            f16x8 vk = *(const f16x8*)(Kh + (size_t)(key0 + r) * DKH + (t & 7) * 8);
            *(f16x8*)(Ks + r * KLDS + (t & 7) * 8) = vk;
            f16x8 vv = *(const f16x8*)(Vh + (size_t)r * S_LEN + key0 + (t & 7) * 8);
            *(f16x8*)(Vs + r * KLDS + (t & 7) * 8) = vv;
        }
        __syncthreads();

        f32x4 sacc[2][4] = {};
#pragma unroll
        for (int ks = 0; ks < 2; ++ks) {
            f16x8 bk[4];
#pragma unroll
            for (int kf = 0; kf < 4; ++kf)
                bk[kf] = *(const f16x8*)(Ks + (kf * 16 + l16) * KLDS + ks * 32 + g * 8);
#pragma unroll
            for (int qfi = 0; qfi < 2; ++qfi)
#pragma unroll
                for (int kf = 0; kf < 4; ++kf)
                    sacc[qfi][kf] = mfma16(qf_[qfi][ks], bk[kf], sacc[qfi][kf]);
        }

#pragma unroll
        for (int qfi = 0; qfi < 2; ++qfi)
#pragma unroll
            for (int kf = 0; kf < 4; ++kf)
#pragma unroll
                for (int r = 0; r < 4; ++r) {
                    float p = exp2f(sacc[qfi][kf][r] * sc - m_[qfi][r]) * l_[qfi][r];
                    int qloc = w * 32 + qfi * 16 + g * 4 + r;
                    attn_h[(size_t)(q0 + qloc) * S_LEN + key0 + kf * 16 + l16] = p;
                    Ps[qloc * KLDS + kf * 16 + l16] = (f16)p;
                }
        __syncthreads();

#pragma unroll
        for (int ks = 0; ks < 2; ++ks) {
            f16x8 bv[4], ap[2];
#pragma unroll
            for (int df = 0; df < 4; ++df)
                bv[df] = *(const f16x8*)(Vs + (df * 16 + l16) * KLDS + ks * 32 + g * 8);
#pragma unroll
            for (int qfi = 0; qfi < 2; ++qfi)
                ap[qfi] = *(const f16x8*)(Ps + (w * 32 + qfi * 16 + l16) * KLDS + ks * 32 + g * 8);
#pragma unroll
            for (int qfi = 0; qfi < 2; ++qfi)
#pragma unroll
                for (int df = 0; df < 4; ++df)
                    oacc[qfi][df] = mfma16(ap[qfi], bv[df], oacc[qfi][df]);
        }
    }

    // write out_heads (f16) in [b*S + s][h*64 + d] layout for the final GEMM
    const int b_idx = bh >> 4;
    const int h_idx = bh & 15;
#pragma unroll
    for (int qfi = 0; qfi < 2; ++qfi)
#pragma unroll
        for (int df = 0; df < 4; ++df)
#pragma unroll
            for (int r = 0; r < 4; ++r) {
                int qq = q0 + w * 32 + qfi * 16 + g * 4 + r;
                int e = h_idx * 64 + df * 16 + l16;
                OH[(size_t)(b_idx * S_LEN + qq) * DMODEL + e] = (f16)oacc[qfi][df][r];
            }
}

// ---------------- Output GEMM: out = OH(f16) @ W_o^T + b_o  (fp32 out)
__global__ __launch_bounds__(256)
void out_gemm(const f16* __restrict__ A, const float* __restrict__ W,
              const float* __restrict__ bias, float* __restrict__ C)
{
    __shared__ f16 As[128 * LDSA];
    __shared__ f16 Bs[128 * LDSA];

    const int t = threadIdx.x;
    const int lane = t & 63;
    const int w = t >> 6;
    const int wr = w >> 1, wc = w & 1;
    const int g = lane >> 4;
    const int l16 = lane & 15;

    const int m0 = blockIdx.y * 128;
    const int n0 = blockIdx.x * 128;

    f32x4 acc[4][4] = {};

    for (int k0 = 0; k0 < DMODEL; k0 += 32) {
#pragma unroll
        for (int it = 0; it < 2; ++it) {
            int r = (t >> 2) + it * 64;
            f16x8 va = *(const f16x8*)(A + (size_t)(m0 + r) * DMODEL + k0 + (t & 3) * 8);
            *(f16x8*)(As + r * LDSA + (t & 3) * 8) = va;
        }
#pragma unroll
        for (int it = 0; it < 4; ++it) {
            int r = (t >> 3) + it * 32;
            float4 vb = *(const float4*)(W + (size_t)(n0 + r) * DMODEL + k0 + (t & 7) * 4);
            f16x4 hb = { (f16)vb.x, (f16)vb.y, (f16)vb.z, (f16)vb.w };
            *(f16x4*)(Bs + r * LDSA + (t & 7) * 4) = hb;
        }
        __syncthreads();
        f16x8 af[4], bf[4];
#pragma unroll
        for (int i = 0; i < 4; ++i) {
            af[i] = *(const f16x8*)(As + (wr * 64 + i * 16 + l16) * LDSA + g * 8);
            bf[i] = *(const f16x8*)(Bs + (wc * 64 + i * 16 + l16) * LDSA + g * 8);
        }
#pragma unroll
        for (int i = 0; i < 4; ++i)
#pragma unroll
            for (int j = 0; j < 4; ++j)
                acc[i][j] = mfma16(af[i], bf[j], acc[i][j]);
        __syncthreads();
    }

#pragma unroll
    for (int j = 0; j < 4; ++j) {
        int n = n0 + wc * 64 + j * 16 + l16;
        float bv = bias[n];
#pragma unroll
        for (int i = 0; i < 4; ++i)
#pragma unroll
            for (int r = 0; r < 4; ++r) {
                int m = m0 + wr * 64 + i * 16 + g * 4 + r;
                C[(size_t)m * DMODEL + n] = acc[i][j][r] + bv;
            }
    }
}

extern "C" void kernel_launch(void* const* d_in, const int* in_sizes, int n_in,
                              void* d_out, int out_size, void* d_ws, size_t ws_size,
                              hipStream_t stream) {
    (void)in_sizes; (void)n_in; (void)out_size; (void)ws_size;

    const float* q  = (const float*)d_in[0];
    const float* k  = (const float*)d_in[1];
    const float* v  = (const float*)d_in[2];
    const float* wq = (const float*)d_in[3];
    const float* bq = (const float*)d_in[4];
    const float* wk = (const float*)d_in[5];
    const float* bk = (const float*)d_in[6];
    const float* wv = (const float*)d_in[7];
    const float* bv = (const float*)d_in[8];
    const float* wo = (const float*)d_in[9];
    const float* bo = (const float*)d_in[10];

    const size_t NELEM = (size_t)4096 * 1024;   // 4,194,304
    f16* q_ws  = (f16*)d_ws;
    f16* k_ws  = q_ws + NELEM;
    f16* v_ws  = k_ws + NELEM;
    f16* oh_ws = v_ws + NELEM;

    float* out  = (float*)d_out;
    float* attn = out + NELEM;                  // [2,16,2048,2048]

    proj_gemm<<<dim3(8, 32, 3), 256, 0, stream>>>(q, k, v, wq, wk, wv, bq, bk, bv,
                                                  q_ws, k_ws, v_ws);
    attn_kernel<<<dim3(16, 32), 256, 0, stream>>>(q_ws, k_ws, v_ws, attn, oh_ws);
    out_gemm<<<dim3(8, 32), 256, 0, stream>>>(oh_ws, wo, bo, out);
}